// Round 6
// baseline (102.969 us; speedup 1.0000x reference)
//
#include <hip/hip_runtime.h>
#include <math.h>

#define TDIM 512
#define KDIM 8
#define DDIM 8
#define BDIM 2048

#define PSTRIDE 76   // per (t,k): rT[j*8+i] (64), off[8], slc, pad[3]
#define XSTRIDE 132  // LDS row stride (128 data floats + 4 pad)

#ifndef __has_builtin
#define __has_builtin(x) 0
#endif
#if __has_builtin(__builtin_amdgcn_exp2f)
#define FAST_EXP2(x) __builtin_amdgcn_exp2f(x)
#else
#define FAST_EXP2(x) exp2f(x)
#endif

// ---------------- Precompute: 8-lane-parallel f32 Cayley + folded constants ----------
// rT[j][i] = q[i][j]*invstd_j*sqrt(0.5*log2e); off_j = c . rT_j;
// slc = log2(w_k) + sum_j log2(nc_j); p_k = 2^(slc - sum_j u_j^2), u_j = x.rT_j - off_j.
__global__ __launch_bounds__(512) void precompute_kernel(
    const float* __restrict__ centers,   // [T,K,8]
    const float* __restrict__ wlogits,   // [T,K]
    const float* __restrict__ logvar,    // [T,K,8]
    const float* __restrict__ covp,      // [T,K,28]
    float* __restrict__ P)               // [T*K*PSTRIDE]
{
    const int tid = (int)blockIdx.x * 512 + (int)threadIdx.x;
    const int tk  = tid >> 3;            // 0..4095 = (t,k)
    const int r   = tid & 7;             // row of the 8x8 system
    const size_t tkg = (size_t)tk;

    // row r of M = I + A ; A = 0.5*(UT^T - UT), UT strict-upper from
    // flat(n) = v[n] (n<28) | v[55-n] (28<=n<56), n = 8*min+max.
    const float* cb = covp + tkg * 28;
    float row[8];
    #pragma unroll
    for (int j = 0; j < 8; j++) {
        const int lo = (r < j) ? r : j;
        const int hi = (r < j) ? j : r;
        const int n  = 8 * lo + hi;
        const int m  = (r == j) ? 0 : ((n < 28) ? n : 55 - n);
        const float v = cb[m];
        const float a = (r < j) ? -0.5f * v : 0.5f * v;
        row[j] = (r == j) ? 1.0f : a;
    }

    // In-place Gauss-Jordan inversion, row-parallel across 8 lanes.
    // (inverse accumulates through the pivot COLUMN — verified round 4)
    #pragma unroll
    for (int c = 0; c < 8; c++) {
        float prow[8];
        #pragma unroll
        for (int j = 0; j < 8; j++) prow[j] = __shfl(row[j], c, 8);
        const float pinv = 1.0f / prow[c];
        const float f = row[c];
        #pragma unroll
        for (int j = 0; j < 8; j++) {
            if (j == c) {
                row[j] = (r == c) ? pinv : -f * pinv;
            } else {
                const float spiv = prow[j] * pinv;
                row[j] = (r == c) ? spiv : fmaf(-f, spiv, row[j]);
            }
        }
    }
    // row[] = inv(I+A)[r][*] ; q[r][j] = 2*row[j] - (r==j)

    const float* lvp = logvar + tkg * 8;
    float invstd[8];
    float sumlv = 0.0f;
    #pragma unroll
    for (int j = 0; j < 8; j++) {
        const float lv = fminf(fmaxf(lvp[j], -3.5f), 3.5f);
        sumlv += lv;
        invstd[j] = exp2f(lv * -0.7213475204444817f);  // exp(-lv/2)
    }
    const float cr = centers[tkg * 8 + r];
    float* pp = P + tkg * PSTRIDE;
    float offp[8];
    #pragma unroll
    for (int j = 0; j < 8; j++) {
        const float q = 2.0f * row[j] - (r == j ? 1.0f : 0.0f);
        const float val = q * (invstd[j] * 0.8493218002880191f); // sqrt(0.5*log2e)
        pp[j * 8 + r] = val;
        offp[j] = cr * val;
    }
    #pragma unroll
    for (int j = 0; j < 8; j++) {
        offp[j] += __shfl_xor(offp[j], 1, 8);
        offp[j] += __shfl_xor(offp[j], 2, 8);
        offp[j] += __shfl_xor(offp[j], 4, 8);
    }

    // softmax over k (k = lane bits 3..5) -> log2(w) directly
    float l = fminf(fmaxf(wlogits[tkg], -3.5f), 3.5f);
    float mx = l;
    mx = fmaxf(mx, __shfl_xor(mx, 8, 64));
    mx = fmaxf(mx, __shfl_xor(mx, 16, 64));
    mx = fmaxf(mx, __shfl_xor(mx, 32, 64));
    const float e = exp2f((l - mx) * 1.4426950408889634f);
    float ss = e;
    ss += __shfl_xor(ss, 8, 64);
    ss += __shfl_xor(ss, 16, 64);
    ss += __shfl_xor(ss, 32, 64);
    const float log2w = (l - mx) * 1.4426950408889634f - log2f(ss);

    if (r == 0) {
        #pragma unroll
        for (int j = 0; j < 8; j++) pp[64 + j] = offp[j];
        // sum_j log2(nc_j) = 8*log2(1/sqrt(2pi)) - log2e/2 * sum_j lv_j
        pp[72] = log2w - 10.605984517349169f - 0.7213475204444817f * sumlv;
    }
}

// ---------------- Main: LDS-staged coalesced x, lane<->b, wave<->2 t's, s_load params,
//                  coalesced stores via LDS transpose (reusing the staging buffer) -----
__global__ __launch_bounds__(512, 8) void pecd_main(
    const float* __restrict__ x,   // [B,T,8]
    const float* __restrict__ P,   // [T*K*PSTRIDE]
    float* __restrict__ out)       // [B,T]
{
    __shared__ float xs[64 * XSTRIDE];   // 33.8 KB; reused as 64x18 out-transpose buffer

    const int tidx = (int)threadIdx.x;
    const int wv   = tidx >> 6;
    const int ln   = tidx & 63;
    const int t0   = (int)blockIdx.x * 16;   // t-tile 16
    const int b0   = (int)blockIdx.y * 64;   // b-tile 64 (lane<->b)

    // ---- stage x[b0:b0+64, t0:t0+16, :] (32 KB) coalesced: 4 passes x 8 KB ----
    #pragma unroll
    for (int it = 0; it < 4; it++) {
        const int idx = tidx + it * 512;     // 0..2047 float4s
        const int row = idx >> 5;            // b-row 0..63
        const int col = idx & 31;            // float4 within 512-B row slice
        const float4 v =
            *((const float4*)(x + ((size_t)(b0 + row) * TDIM + t0) * DDIM) + col);
        *(float4*)(xs + row * XSTRIDE + col * 4) = v;
    }
    __syncthreads();

    // ---- pull this lane's two t-fragments into registers (before any xs reuse) ----
    float xv[2][8];
    #pragma unroll
    for (int tt = 0; tt < 2; tt++) {
        const float* xr = xs + ln * XSTRIDE + (wv * 2 + tt) * 8;
        const float4 a0 = *(const float4*)(xr);
        const float4 a1 = *(const float4*)(xr + 4);
        xv[tt][0] = a0.x; xv[tt][1] = a0.y; xv[tt][2] = a0.z; xv[tt][3] = a0.w;
        xv[tt][4] = a1.x; xv[tt][5] = a1.y; xv[tt][6] = a1.z; xv[tt][7] = a1.w;
    }

    float accs[2];
    #pragma unroll
    for (int tt = 0; tt < 2; tt++) {
        const int ts = __builtin_amdgcn_readfirstlane(t0 + wv * 2 + tt);
        const float* __restrict__ pt = P + (size_t)ts * (KDIM * PSTRIDE);
        float acc = 0.0f;
        #pragma unroll 1
        for (int k = 0; k < KDIM; k++) {
            const float* pk = pt + k * PSTRIDE;   // wave-uniform -> s_loads
            float s0 = 0.0f, s1 = 0.0f;
            #pragma unroll
            for (int j = 0; j < 8; j++) {
                float u = -pk[64 + j];
                #pragma unroll
                for (int i = 0; i < 8; i++) u = fmaf(xv[tt][i], pk[j * 8 + i], u);
                if (j & 1) s1 = fmaf(u, u, s1);
                else       s0 = fmaf(u, u, s0);
            }
            acc += FAST_EXP2(pk[72] - s0 - s1);
        }
        accs[tt] = acc;
    }

    // ---- transpose through LDS (reuse xs) for coalesced 64-B stores ----
    __syncthreads();   // all waves done reading xs
    xs[ln * 18 + wv * 2 + 0] = accs[0];
    xs[ln * 18 + wv * 2 + 1] = accs[1];
    __syncthreads();
    {
        const int row = tidx >> 3;       // b 0..63
        const int col = tidx & 7;        // float2 within 16-t row
        const float2 v = *(const float2*)&xs[row * 18 + col * 2];
        *(float2*)(out + (size_t)(b0 + row) * TDIM + t0 + col * 2) = v;
    }
}

extern "C" void kernel_launch(void* const* d_in, const int* in_sizes, int n_in,
                              void* d_out, int out_size, void* d_ws, size_t ws_size,
                              hipStream_t stream) {
    const float* x       = (const float*)d_in[0];  // [2048,512,8]
    const float* centers = (const float*)d_in[1];  // [512,8,8]
    const float* wlogits = (const float*)d_in[2];  // [512,8]
    const float* logvar  = (const float*)d_in[3];  // [512,8,8]
    const float* covp    = (const float*)d_in[4];  // [512,8,28]
    float* out = (float*)d_out;                    // [2048,512]

    float* P = (float*)d_ws;                       // 4096*76 floats = 1.24 MB

    precompute_kernel<<<dim3(TDIM * KDIM * 8 / 512), dim3(512), 0, stream>>>(
        centers, wlogits, logvar, covp, P);

    dim3 grid(TDIM / 16, BDIM / 64);               // (32, 32) = 1024 blocks
    pecd_main<<<grid, dim3(512), 0, stream>>>(x, P, out);
}

// Round 7
// 96.404 us; speedup vs baseline: 1.0681x; 1.0681x over previous
//
#include <hip/hip_runtime.h>
#include <math.h>

#define TDIM 512
#define KDIM 8
#define DDIM 8
#define BDIM 2048

#define PSTRIDE 48   // per (t,k): 8 i-blocks [lin_i, S'_ii, 2S'_i,i+1.. ] (44), const, pad3
#define XSTRIDE 132  // LDS row stride (128 data floats + 4 pad)

#ifndef __has_builtin
#define __has_builtin(x) 0
#endif
#if __has_builtin(__builtin_amdgcn_exp2f)
#define FAST_EXP2(x) __builtin_amdgcn_exp2f(x)
#else
#define FAST_EXP2(x) exp2f(x)
#endif

// ---------------- Precompute: 8-lane-parallel f32 Cayley -> quadratic-form coefs -------
// Sum_j u_j^2 = (x-c)^T S (x-c), S = Q diag(0.7213*e^lv) Q^T (log2e/2 folded in).
// Stored per (t,k): e(x) = const + sum_i x_i*(lin_i + sum_{j>=i} S'_ij x_j),
// S'_ii = S_ii, S'_ij = 2 S_ij (i<j); lin = -2 S c; const = c^T S c - slc;
// slc = log2(w_k) + sum_j log2(nc_j).  p_k = 2^(-e).
__global__ __launch_bounds__(512) void precompute_kernel(
    const float* __restrict__ centers,   // [T,K,8]
    const float* __restrict__ wlogits,   // [T,K]
    const float* __restrict__ logvar,    // [T,K,8]
    const float* __restrict__ covp,      // [T,K,28]
    float* __restrict__ P)               // [T*K*PSTRIDE]
{
    const int tid = (int)blockIdx.x * 512 + (int)threadIdx.x;
    const int tk  = tid >> 3;            // 0..4095 = (t,k)
    const int r   = tid & 7;             // row of the 8x8 system
    const size_t tkg = (size_t)tk;

    // row r of M = I + A ; A = 0.5*(UT^T - UT), UT strict-upper from
    // flat(n) = v[n] (n<28) | v[55-n] (28<=n<56), n = 8*min+max.
    const float* cb = covp + tkg * 28;
    float row[8];
    #pragma unroll
    for (int j = 0; j < 8; j++) {
        const int lo = (r < j) ? r : j;
        const int hi = (r < j) ? j : r;
        const int n  = 8 * lo + hi;
        const int m  = (r == j) ? 0 : ((n < 28) ? n : 55 - n);
        const float v = cb[m];
        const float a = (r < j) ? -0.5f * v : 0.5f * v;
        row[j] = (r == j) ? 1.0f : a;
    }

    // In-place Gauss-Jordan inversion, row-parallel across 8 lanes.
    // (inverse accumulates through the pivot COLUMN — verified round 4)
    #pragma unroll
    for (int c = 0; c < 8; c++) {
        float prow[8];
        #pragma unroll
        for (int j = 0; j < 8; j++) prow[j] = __shfl(row[j], c, 8);
        const float pinv = 1.0f / prow[c];
        const float f = row[c];
        #pragma unroll
        for (int j = 0; j < 8; j++) {
            if (j == c) {
                row[j] = (r == c) ? pinv : -f * pinv;
            } else {
                const float spiv = prow[j] * pinv;
                row[j] = (r == c) ? spiv : fmaf(-f, spiv, row[j]);
            }
        }
    }
    // q[r][j] = 2*row[j] - (r==j)
    float qr[8];
    #pragma unroll
    for (int j = 0; j < 8; j++) qr[j] = 2.0f * row[j] - (r == j ? 1.0f : 0.0f);

    // sc2_j = 0.5*log2e * var_j^-1 ... wait: u_j includes sqrt(0.5 log2e)*invstd_j,
    // so sc2_j = 0.7213475 * exp(-lv_j) and S = Q diag(sc2) Q^T.
    const float* lvp = logvar + tkg * 8;
    float sc2[8];
    float sumlv = 0.0f;
    #pragma unroll
    for (int j = 0; j < 8; j++) {
        const float lv = fminf(fmaxf(lvp[j], -3.5f), 3.5f);
        sumlv += lv;
        sc2[j] = 0.7213475204444817f * exp2f(lv * -1.4426950408889634f);
    }
    float w[8];
    #pragma unroll
    for (int j = 0; j < 8; j++) w[j] = qr[j] * sc2[j];

    // S_rm = sum_j w[j] * q[m][j]   (q[m][*] via shfl within the 8-lane group)
    float Srow[8];
    #pragma unroll
    for (int m = 0; m < 8; m++) {
        float s = 0.0f;
        #pragma unroll
        for (int j = 0; j < 8; j++) s = fmaf(w[j], __shfl(qr[j], m, 8), s);
        Srow[m] = s;
    }

    // lin_r = -2 (S c)_r ; cSc = sum_r c_r (S c)_r
    const float* cp = centers + tkg * 8;
    float cvec[8];
    #pragma unroll
    for (int m = 0; m < 8; m++) cvec[m] = cp[m];
    float tr = 0.0f;
    #pragma unroll
    for (int m = 0; m < 8; m++) tr = fmaf(Srow[m], cvec[m], tr);
    const float lin = -2.0f * tr;
    float cpart = cp[r] * tr;
    cpart += __shfl_xor(cpart, 1, 8);
    cpart += __shfl_xor(cpart, 2, 8);
    cpart += __shfl_xor(cpart, 4, 8);   // = c^T S c (all lanes)

    // softmax over k (k = lane bits 3..5) -> log2(w) directly
    float l = fminf(fmaxf(wlogits[tkg], -3.5f), 3.5f);
    float mx = l;
    mx = fmaxf(mx, __shfl_xor(mx, 8, 64));
    mx = fmaxf(mx, __shfl_xor(mx, 16, 64));
    mx = fmaxf(mx, __shfl_xor(mx, 32, 64));
    const float e = exp2f((l - mx) * 1.4426950408889634f);
    float ss = e;
    ss += __shfl_xor(ss, 8, 64);
    ss += __shfl_xor(ss, 16, 64);
    ss += __shfl_xor(ss, 32, 64);
    const float log2w = (l - mx) * 1.4426950408889634f - log2f(ss);
    // slc = log2w + 8*log2(1/sqrt(2pi)) - log2e/2 * sum lv
    const float slc = log2w - 10.605984517349169f - 0.7213475204444817f * sumlv;

    // ---- write i-block-major coefficients ----
    float* pp = P + tkg * PSTRIDE;
    const int o = 9 * r - (r * (r - 1)) / 2;   // 0,9,17,24,30,35,39,42
    pp[o] = lin;
    #pragma unroll
    for (int j = 0; j < 8; j++) {
        if (j >= r) pp[o + 1 + j - r] = Srow[j] * ((j == r) ? 1.0f : 2.0f);
    }
    if (r == 0) pp[44] = cpart - slc;
}

// ---------------- Main: LDS-staged coalesced x, lane<->b, wave<->2 t's, s_load coefs,
//                  symmetric-Horner quadratic form (44 FMA/k), coalesced stores ---------
__global__ __launch_bounds__(512, 8) void pecd_main(
    const float* __restrict__ x,   // [B,T,8]
    const float* __restrict__ P,   // [T*K*PSTRIDE]
    float* __restrict__ out)       // [B,T]
{
    __shared__ float xs[64 * XSTRIDE];   // 33.8 KB; reused as 64x18 out-transpose buffer

    const int tidx = (int)threadIdx.x;
    const int wv   = tidx >> 6;
    const int ln   = tidx & 63;
    const int t0   = (int)blockIdx.x * 16;   // t-tile 16
    const int b0   = (int)blockIdx.y * 64;   // b-tile 64 (lane<->b)

    // ---- stage x[b0:b0+64, t0:t0+16, :] (32 KB) coalesced: 4 passes x 8 KB ----
    #pragma unroll
    for (int it = 0; it < 4; it++) {
        const int idx = tidx + it * 512;     // 0..2047 float4s
        const int rowi = idx >> 5;           // b-row 0..63
        const int col  = idx & 31;           // float4 within 512-B row slice
        const float4 v =
            *((const float4*)(x + ((size_t)(b0 + rowi) * TDIM + t0) * DDIM) + col);
        *(float4*)(xs + rowi * XSTRIDE + col * 4) = v;
    }
    __syncthreads();

    float accs[2];
    #pragma unroll
    for (int tt = 0; tt < 2; tt++) {
        const int ts = __builtin_amdgcn_readfirstlane(t0 + wv * 2 + tt);
        const float* __restrict__ pt = P + (size_t)ts * (KDIM * PSTRIDE);

        const float* xr = xs + ln * XSTRIDE + (wv * 2 + tt) * 8;
        const float4 a0 = *(const float4*)(xr);
        const float4 a1 = *(const float4*)(xr + 4);
        const float xv[8] = {a0.x, a0.y, a0.z, a0.w, a1.x, a1.y, a1.z, a1.w};

        float acc = 0.0f;
        #pragma unroll 2
        for (int k = 0; k < KDIM; k++) {
            const float* pk = pt + k * PSTRIDE;   // wave-uniform -> s_loads
            float e0 = pk[44], e1 = 0.0f, e2 = 0.0f, e3 = 0.0f;
            #pragma unroll
            for (int i = 0; i < 8; i++) {
                const int o = 9 * i - (i * (i - 1)) / 2;
                float inner = pk[o];                       // lin_i
                #pragma unroll
                for (int j = i; j < 8; j++)
                    inner = fmaf(pk[o + 1 + j - i], xv[j], inner);
                if ((i & 3) == 0)      e0 = fmaf(xv[i], inner, e0);
                else if ((i & 3) == 1) e1 = fmaf(xv[i], inner, e1);
                else if ((i & 3) == 2) e2 = fmaf(xv[i], inner, e2);
                else                   e3 = fmaf(xv[i], inner, e3);
            }
            acc += FAST_EXP2(-((e0 + e1) + (e2 + e3)));
        }
        accs[tt] = acc;
    }

    // ---- transpose through LDS (reuse xs) for coalesced 64-B stores ----
    __syncthreads();   // all waves done reading xs
    xs[ln * 18 + wv * 2 + 0] = accs[0];
    xs[ln * 18 + wv * 2 + 1] = accs[1];
    __syncthreads();
    {
        const int rowi = tidx >> 3;      // b 0..63
        const int col  = tidx & 7;       // float2 within 16-t row
        const float2 v = *(const float2*)&xs[rowi * 18 + col * 2];
        *(float2*)(out + (size_t)(b0 + rowi) * TDIM + t0 + col * 2) = v;
    }
}

extern "C" void kernel_launch(void* const* d_in, const int* in_sizes, int n_in,
                              void* d_out, int out_size, void* d_ws, size_t ws_size,
                              hipStream_t stream) {
    const float* x       = (const float*)d_in[0];  // [2048,512,8]
    const float* centers = (const float*)d_in[1];  // [512,8,8]
    const float* wlogits = (const float*)d_in[2];  // [512,8]
    const float* logvar  = (const float*)d_in[3];  // [512,8,8]
    const float* covp    = (const float*)d_in[4];  // [512,8,28]
    float* out = (float*)d_out;                    // [2048,512]

    float* P = (float*)d_ws;                       // 4096*48 floats = 786 KB

    precompute_kernel<<<dim3(TDIM * KDIM * 8 / 512), dim3(512), 0, stream>>>(
        centers, wlogits, logvar, covp, P);

    dim3 grid(TDIM / 16, BDIM / 64);               // (32, 32) = 1024 blocks
    pecd_main<<<grid, dim3(512), 0, stream>>>(x, P, out);
}

// Round 8
// 93.087 us; speedup vs baseline: 1.1062x; 1.0356x over previous
//
#include <hip/hip_runtime.h>
#include <math.h>

#define TDIM 512
#define KDIM 8
#define DDIM 8
#define BDIM 2048

#define PSTRIDE 48   // per tk: 8 i-blocks [lin_i, S'_ii, 2S'_ij...] (44), const, pad3
#define XSTRIDE 68   // x staging row stride

#ifndef __has_builtin
#define __has_builtin(x) 0
#endif
#if __has_builtin(__builtin_amdgcn_exp2f)
#define FAST_EXP2(x) __builtin_amdgcn_exp2f(x)
#else
#define FAST_EXP2(x) exp2f(x)
#endif

// Single fused kernel.
// Phase A (512 thr = 64 tk x 8 rows): 8-lane-parallel f32 Gauss-Jordan Cayley
//   (in-place, inverse accumulates through pivot COLUMN — verified R4), then
//   S = Q diag(0.7213*e^-lv) Q^T, folded into quadratic-form coefs in LDS:
//   e(x) = const + sum_i x_i*(lin_i + sum_{j>=i} S'_ij x_j); p_k = 2^(-e).
// Phase B: wave<->t, lane<->b, 4-b register blocking; x staged coalesced via
//   LDS; coefs read wave-uniform from LDS (broadcast); coalesced stores via
//   LDS transpose.
__global__ __launch_bounds__(512, 4) void pecd_fused(
    const float* __restrict__ x,         // [B,T,8]
    const float* __restrict__ centers,   // [T,K,8]
    const float* __restrict__ wlogits,   // [T,K]
    const float* __restrict__ logvar,    // [T,K,8]
    const float* __restrict__ covp,      // [T,K,28]
    float* __restrict__ out)             // [B,T]
{
    __shared__ float prm[64 * PSTRIDE];  // 12.3 KB coefs
    __shared__ float xs[64 * XSTRIDE];   // 17.4 KB staging; reused as 256x9 out buffer

    const int tidx = (int)threadIdx.x;
    const int t0   = (int)blockIdx.x * 8;     // wave w handles t0+w
    const int b0   = (int)blockIdx.y * 256;   // 4 chunks of 64 b

    // ================= Phase A =================
    {
        const int tk = tidx >> 3;             // 0..63 = (t_local, k); t_local == wave
        const int r  = tidx & 7;
        const size_t tkg = (size_t)(t0 + (tk >> 3)) * 8 + (tk & 7);

        // row r of M = I + A ; A = 0.5*(UT^T - UT), UT strict-upper from
        // flat(n) = v[n] (n<28) | v[55-n] (28<=n<56), n = 8*min+max.
        const float* cb = covp + tkg * 28;
        float row[8];
        #pragma unroll
        for (int j = 0; j < 8; j++) {
            const int lo = (r < j) ? r : j;
            const int hi = (r < j) ? j : r;
            const int n  = 8 * lo + hi;
            const int m  = (r == j) ? 0 : ((n < 28) ? n : 55 - n);
            const float v = cb[m];
            const float a = (r < j) ? -0.5f * v : 0.5f * v;
            row[j] = (r == j) ? 1.0f : a;
        }

        #pragma unroll
        for (int c = 0; c < 8; c++) {
            float prow[8];
            #pragma unroll
            for (int j = 0; j < 8; j++) prow[j] = __shfl(row[j], c, 8);
            const float pinv = 1.0f / prow[c];
            const float f = row[c];
            #pragma unroll
            for (int j = 0; j < 8; j++) {
                if (j == c) {
                    row[j] = (r == c) ? pinv : -f * pinv;
                } else {
                    const float spiv = prow[j] * pinv;
                    row[j] = (r == c) ? spiv : fmaf(-f, spiv, row[j]);
                }
            }
        }
        float qr[8];
        #pragma unroll
        for (int j = 0; j < 8; j++) qr[j] = 2.0f * row[j] - (r == j ? 1.0f : 0.0f);

        const float* lvp = logvar + tkg * 8;
        float sc2[8];
        float sumlv = 0.0f;
        #pragma unroll
        for (int j = 0; j < 8; j++) {
            const float lv = fminf(fmaxf(lvp[j], -3.5f), 3.5f);
            sumlv += lv;
            sc2[j] = 0.7213475204444817f * exp2f(lv * -1.4426950408889634f);
        }
        float w[8];
        #pragma unroll
        for (int j = 0; j < 8; j++) w[j] = qr[j] * sc2[j];

        float Srow[8];
        #pragma unroll
        for (int m = 0; m < 8; m++) {
            float s = 0.0f;
            #pragma unroll
            for (int j = 0; j < 8; j++) s = fmaf(w[j], __shfl(qr[j], m, 8), s);
            Srow[m] = s;
        }

        const float* cp = centers + tkg * 8;
        float tr = 0.0f;
        #pragma unroll
        for (int m = 0; m < 8; m++) tr = fmaf(Srow[m], cp[m], tr);
        const float lin = -2.0f * tr;
        float cpart = cp[r] * tr;
        cpart += __shfl_xor(cpart, 1, 8);
        cpart += __shfl_xor(cpart, 2, 8);
        cpart += __shfl_xor(cpart, 4, 8);   // = c^T S c

        // softmax over k (k = tid bits 3..5, within-wave) -> log2(w)
        float l = fminf(fmaxf(wlogits[tkg], -3.5f), 3.5f);
        float mx = l;
        mx = fmaxf(mx, __shfl_xor(mx, 8, 64));
        mx = fmaxf(mx, __shfl_xor(mx, 16, 64));
        mx = fmaxf(mx, __shfl_xor(mx, 32, 64));
        const float e = exp2f((l - mx) * 1.4426950408889634f);
        float ss = e;
        ss += __shfl_xor(ss, 8, 64);
        ss += __shfl_xor(ss, 16, 64);
        ss += __shfl_xor(ss, 32, 64);
        const float log2w = (l - mx) * 1.4426950408889634f - log2f(ss);
        const float slc = log2w - 10.605984517349169f - 0.7213475204444817f * sumlv;

        float* pp = prm + tk * PSTRIDE;
        const int o = 9 * r - (r * (r - 1)) / 2;   // 0,9,17,24,30,35,39,42
        pp[o] = lin;
        #pragma unroll
        for (int j = 0; j < 8; j++) {
            if (j >= r) pp[o + 1 + j - r] = Srow[j] * ((j == r) ? 1.0f : 2.0f);
        }
        if (r == 0) pp[44] = cpart - slc;
    }

    // ================= Phase B =================
    const int wv = tidx >> 6;
    const int ln = tidx & 63;

    // stage 4 chunks of x coalesced; keep 4 b-rows per lane in registers
    float xv[4][8];
    #pragma unroll
    for (int c = 0; c < 4; c++) {
        __syncthreads();   // protects xs reuse; first one also publishes prm
        #pragma unroll
        for (int it = 0; it < 2; it++) {
            const int idx = tidx + it * 512;    // 0..1023 float4s
            const int row = idx >> 4;           // b-row 0..63
            const int col = idx & 15;
            const float4 v =
                *((const float4*)(x + ((size_t)(b0 + c * 64 + row) * TDIM + t0) * DDIM) + col);
            *(float4*)(xs + row * XSTRIDE + col * 4) = v;
        }
        __syncthreads();
        const float* xr = xs + ln * XSTRIDE + wv * 8;
        const float4 a0 = *(const float4*)(xr);
        const float4 a1 = *(const float4*)(xr + 4);
        xv[c][0] = a0.x; xv[c][1] = a0.y; xv[c][2] = a0.z; xv[c][3] = a0.w;
        xv[c][4] = a1.x; xv[c][5] = a1.y; xv[c][6] = a1.z; xv[c][7] = a1.w;
    }

    float acc[4] = {0.f, 0.f, 0.f, 0.f};
    #pragma unroll 2
    for (int k = 0; k < KDIM; k++) {
        const float* pk = prm + (wv * 8 + k) * PSTRIDE;  // wave-uniform -> broadcast
        const float cst = pk[44];
        float ee[4] = {cst, cst, cst, cst};
        #pragma unroll
        for (int i = 0; i < 8; i++) {
            const int o = 9 * i - (i * (i - 1)) / 2;
            const float lin = pk[o];
            float inner[4] = {lin, lin, lin, lin};
            #pragma unroll
            for (int j = i; j < 8; j++) {
                const float cf = pk[o + 1 + j - i];
                #pragma unroll
                for (int c = 0; c < 4; c++) inner[c] = fmaf(cf, xv[c][j], inner[c]);
            }
            #pragma unroll
            for (int c = 0; c < 4; c++) ee[c] = fmaf(xv[c][i], inner[c], ee[c]);
        }
        #pragma unroll
        for (int c = 0; c < 4; c++) acc[c] += FAST_EXP2(-ee[c]);
    }

    // ---- transpose through LDS (reuse xs: 256 rows x 9 = 9.2 KB) ----
    __syncthreads();   // all xs staging reads done
    #pragma unroll
    for (int c = 0; c < 4; c++)
        xs[(c * 64 + ln) * 9 + wv] = acc[c];   // stride 9: conflict-free (9 coprime 32)
    __syncthreads();
    {
        const int row  = tidx >> 1;    // 0..255 local b
        const int part = tidx & 1;     // float4 half of the 8-t row
        float4 v;
        v.x = xs[row * 9 + part * 4 + 0];
        v.y = xs[row * 9 + part * 4 + 1];
        v.z = xs[row * 9 + part * 4 + 2];
        v.w = xs[row * 9 + part * 4 + 3];
        *(float4*)(out + (size_t)(b0 + row) * TDIM + t0 + part * 4) = v;
    }
}

extern "C" void kernel_launch(void* const* d_in, const int* in_sizes, int n_in,
                              void* d_out, int out_size, void* d_ws, size_t ws_size,
                              hipStream_t stream) {
    const float* x       = (const float*)d_in[0];  // [2048,512,8]
    const float* centers = (const float*)d_in[1];  // [512,8,8]
    const float* wlogits = (const float*)d_in[2];  // [512,8]
    const float* logvar  = (const float*)d_in[3];  // [512,8,8]
    const float* covp    = (const float*)d_in[4];  // [512,8,28]
    float* out = (float*)d_out;                    // [2048,512]
    (void)d_ws; (void)ws_size;

    dim3 grid(TDIM / 8, BDIM / 256);               // (64, 8) = 512 blocks
    pecd_fused<<<grid, dim3(512), 0, stream>>>(x, centers, wlogits, logvar, covp, out);
}